// Round 2
// baseline (144.105 us; speedup 1.0000x reference)
//
#include <hip/hip_runtime.h>

// Coords are all {0,1}; STRIDES is a mixed-radix positional encoding, so each
// row maps bijectively to a 16-bit pattern. Whole op = 65536-bin float
// histogram (scatter-add) + gather.
//
// R1 change: bins spread to one per 32B sector (STRIDE=8 floats). R0 evidence:
// WRITE_SIZE == n_atomics * 32B -> each device-scope fp atomic writes its own
// 32B sector at the coherence point; 8 bins/sector gave ~254 serialized
// atomics per sector. Spreading cuts serial depth 8x.

#define NBINS 65536
#define REL_W 16

__device__ __forceinline__ unsigned pattern_of(const int* __restrict__ row) {
    const int4* p = reinterpret_cast<const int4*>(row);
    unsigned pat = 0;
#pragma unroll
    for (int k = 0; k < 4; ++k) {
        int4 v = p[k];
        pat |= (unsigned)(v.x & 1) << (k * 4 + 0);
        pat |= (unsigned)(v.y & 1) << (k * 4 + 1);
        pat |= (unsigned)(v.z & 1) << (k * 4 + 2);
        pat |= (unsigned)(v.w & 1) << (k * 4 + 3);
    }
    return pat;
}

template <int STRIDE>
__global__ void build_hist_kernel(const int* __restrict__ coords,
                                  const float* __restrict__ vals,
                                  float* __restrict__ hist, int n) {
    int i = blockIdx.x * blockDim.x + threadIdx.x;
    if (i >= n) return;
    unsigned pat = pattern_of(coords + (size_t)i * REL_W);
    atomicAdd(&hist[(size_t)pat * STRIDE], vals[i]);
}

template <int STRIDE>
__global__ void gather_kernel(const int* __restrict__ queries,
                              const float* __restrict__ hist,
                              float* __restrict__ out, int n) {
    int i = blockIdx.x * blockDim.x + threadIdx.x;
    if (i >= n) return;
    unsigned pat = pattern_of(queries + (size_t)i * REL_W);
    out[i] = hist[(size_t)pat * STRIDE];
}

extern "C" void kernel_launch(void* const* d_in, const int* in_sizes, int n_in,
                              void* d_out, int out_size, void* d_ws, size_t ws_size,
                              hipStream_t stream) {
    const int*   stored  = (const int*)d_in[0];   // [N_store, 16] int32
    const int*   queries = (const int*)d_in[1];   // [N_query, 16] int32
    const float* vals    = (const float*)d_in[2]; // [N_store] f32
    float*       out     = (float*)d_out;         // [N_query] f32
    float*       hist    = (float*)d_ws;

    int n_store = in_sizes[0] / REL_W;
    int n_query = in_sizes[1] / REL_W;

    const int BLK = 256;
    const size_t strided_bytes = (size_t)NBINS * 8 * sizeof(float); // 2 MiB

    if (ws_size >= strided_bytes) {
        hipMemsetAsync(d_ws, 0, strided_bytes, stream);
        build_hist_kernel<8><<<(n_store + BLK - 1) / BLK, BLK, 0, stream>>>(stored, vals, hist, n_store);
        gather_kernel<8><<<(n_query + BLK - 1) / BLK, BLK, 0, stream>>>(queries, hist, out, n_query);
    } else {
        hipMemsetAsync(d_ws, 0, NBINS * sizeof(float), stream);
        build_hist_kernel<1><<<(n_store + BLK - 1) / BLK, BLK, 0, stream>>>(stored, vals, hist, n_store);
        gather_kernel<1><<<(n_query + BLK - 1) / BLK, BLK, 0, stream>>>(queries, hist, out, n_query);
    }
}

// Round 3
// 141.997 us; speedup vs baseline: 1.0148x; 1.0148x over previous
//
#include <hip/hip_runtime.h>

// Coords are all {0,1}; STRIDES is a mixed-radix positional encoding, so each
// row maps bijectively to a 16-bit pattern. Whole op = 65536-bin float
// histogram (scatter-add) + gather.
//
// R2: R0/R1 showed device-scope fp atomics bypass the XCD L2 and execute at
// the memory-side coherence point (WRITE_SIZE == n_atomics*32B, fixed per-op
// cost ~19G/s). Fix: 8 XCD-private histogram copies + WORKGROUP-scope atomics
// (serviced in the XCD-local TCC, which is shared by all blocks on that XCD),
// then a coalesced reduce kernel. Kernel-boundary release makes the dirty L2
// lines visible across XCDs for the reduce.

#define NBINS 65536
#define REL_W 16
#define NXCD 8

__device__ __forceinline__ unsigned pattern_of(const int* __restrict__ row) {
    const int4* p = reinterpret_cast<const int4*>(row);
    unsigned pat = 0;
#pragma unroll
    for (int k = 0; k < 4; ++k) {
        int4 v = p[k];
        pat |= (unsigned)(v.x & 1) << (k * 4 + 0);
        pat |= (unsigned)(v.y & 1) << (k * 4 + 1);
        pat |= (unsigned)(v.z & 1) << (k * 4 + 2);
        pat |= (unsigned)(v.w & 1) << (k * 4 + 3);
    }
    return pat;
}

__device__ __forceinline__ unsigned xcc_id() {
    unsigned x;
    asm volatile("s_getreg_b32 %0, hwreg(HW_REG_XCC_ID)" : "=s"(x));
    return x & (NXCD - 1);
}

__global__ void build_hist_xcd(const int* __restrict__ coords,
                               const float* __restrict__ vals,
                               float* __restrict__ hists, int n) {
    int i = blockIdx.x * blockDim.x + threadIdx.x;
    if (i >= n) return;
    unsigned pat = pattern_of(coords + (size_t)i * REL_W);
    unsigned x = xcc_id();
    __hip_atomic_fetch_add(&hists[(size_t)x * NBINS + pat], vals[i],
                           __ATOMIC_RELAXED, __HIP_MEMORY_SCOPE_WORKGROUP);
}

__global__ void reduce_hists(const float* __restrict__ hists,
                             float* __restrict__ final_h) {
    int b = blockIdx.x * blockDim.x + threadIdx.x; // bin index
    float s = 0.0f;
#pragma unroll
    for (int x = 0; x < NXCD; ++x) s += hists[(size_t)x * NBINS + b];
    final_h[b] = s;
}

// fallback path (R0): single hist, device-scope atomics
__global__ void build_hist_dev(const int* __restrict__ coords,
                               const float* __restrict__ vals,
                               float* __restrict__ hist, int n) {
    int i = blockIdx.x * blockDim.x + threadIdx.x;
    if (i >= n) return;
    unsigned pat = pattern_of(coords + (size_t)i * REL_W);
    atomicAdd(&hist[pat], vals[i]);
}

__global__ void gather_kernel(const int* __restrict__ queries,
                              const float* __restrict__ hist,
                              float* __restrict__ out, int n) {
    int i = blockIdx.x * blockDim.x + threadIdx.x;
    if (i >= n) return;
    unsigned pat = pattern_of(queries + (size_t)i * REL_W);
    out[i] = hist[pat];
}

extern "C" void kernel_launch(void* const* d_in, const int* in_sizes, int n_in,
                              void* d_out, int out_size, void* d_ws, size_t ws_size,
                              hipStream_t stream) {
    const int*   stored  = (const int*)d_in[0];   // [N_store, 16] int32
    const int*   queries = (const int*)d_in[1];   // [N_query, 16] int32
    const float* vals    = (const float*)d_in[2]; // [N_store] f32
    float*       out     = (float*)d_out;         // [N_query] f32

    int n_store = in_sizes[0] / REL_W;
    int n_query = in_sizes[1] / REL_W;

    const int BLK = 256;
    const size_t xcd_bytes = (size_t)(NXCD + 1) * NBINS * sizeof(float); // 2.25 MiB

    if (ws_size >= xcd_bytes) {
        float* hists   = (float*)d_ws;                       // 8 x 64K
        float* final_h = (float*)d_ws + (size_t)NXCD * NBINS; // 64K
        hipMemsetAsync(d_ws, 0, (size_t)NXCD * NBINS * sizeof(float), stream);
        build_hist_xcd<<<(n_store + BLK - 1) / BLK, BLK, 0, stream>>>(stored, vals, hists, n_store);
        reduce_hists<<<NBINS / BLK, BLK, 0, stream>>>(hists, final_h);
        gather_kernel<<<(n_query + BLK - 1) / BLK, BLK, 0, stream>>>(queries, final_h, out, n_query);
    } else {
        float* hist = (float*)d_ws;
        hipMemsetAsync(d_ws, 0, NBINS * sizeof(float), stream);
        build_hist_dev<<<(n_store + BLK - 1) / BLK, BLK, 0, stream>>>(stored, vals, hist, n_store);
        gather_kernel<<<(n_query + BLK - 1) / BLK, BLK, 0, stream>>>(queries, hist, out, n_query);
    }
}